// Round 1
// baseline (953.384 us; speedup 1.0000x reference)
//
#include <hip/hip_runtime.h>
#include <math.h>

// ---------------- sizes ----------------
#define BSZ   8192
#define DDIM  256
#define NCTX  2048
#define NBODY 2048
#define NFACE 512
#define NTEXT 768
#define NCLS  26
#define BN_EPS 1e-5f

// ---------------- workspace layout (in floats) ----------------
static constexpr size_t OFF_F     = 0;                       // 32768*256
static constexpr size_t OFF_SO    = 8388608;                 // 32768*256
static constexpr size_t OFF_COMB  = 0;                       // reuse F region
static constexpr size_t OFF_WVO   = 16777216;                // 256*256
static constexpr size_t OFF_BVO   = OFF_WVO   + 65536;       // 256
static constexpr size_t OFF_GPART = OFF_BVO   + 256;         // 2*32768
static constexpr size_t OFF_GATE  = OFF_GPART + 65536;       // 32768
static constexpr size_t OFF_H     = OFF_GATE  + 32768;       // 8192*256
static constexpr size_t OFF_PSUM  = OFF_H     + 2097152;     // 64*256
static constexpr size_t OFF_PSQ   = OFF_PSUM  + 16384;       // 64*256
static constexpr size_t OFF_SCALE = OFF_PSQ   + 16384;       // 256
static constexpr size_t OFF_SHIFT = OFF_SCALE + 256;         // 256

// ---------------- Wvo = out_w @ Wv, bvo = out_w @ bv + out_b ----------------
__global__ __launch_bounds__(256)
void wvo_kernel(const float* __restrict__ in_w, const float* __restrict__ in_b,
                const float* __restrict__ out_w, const float* __restrict__ out_b,
                float* __restrict__ wvo, float* __restrict__ bvo)
{
    const int i = blockIdx.x;    // output row
    const int j = threadIdx.x;   // output col
    const float* Wv = in_w + 512 * 256;   // third split of in-proj
    float s = 0.f;
    for (int k = 0; k < 256; ++k)
        s = fmaf(out_w[i * 256 + k], Wv[k * 256 + j], s);
    wvo[i * 256 + j] = s;
    if (i == 0) {
        const float* bv = in_b + 512;
        float t = 0.f;
        for (int k = 0; k < 256; ++k)
            t = fmaf(out_w[j * 256 + k], bv[k], t);
        bvo[j] = t + out_b[j];
    }
}

// ---------------- generic NT SGEMM ----------------
// C[r][n] = sum_k A[r*lda+k] * W[n*K+k] + bias[n]
// BM=BN=128, BK=16, 256 threads, 8x8 micro-tile
__global__ __launch_bounds__(256)
void sgemm_nt(const float* __restrict__ A, const float* __restrict__ W,
              const float* __restrict__ bias, float* __restrict__ C,
              int K, int lda, int ldc)
{
    __shared__ float As[16][136];   // [k][m], pad keeps 16B row alignment
    __shared__ float Bs[16][136];   // [k][n]
    const int bm = blockIdx.x * 128;
    const int bn = blockIdx.y * 128;
    const int t  = threadIdx.x;
    const int tx = t & 15, ty = t >> 4;

    float acc[8][8];
#pragma unroll
    for (int i = 0; i < 8; ++i)
#pragma unroll
        for (int j = 0; j < 8; ++j) acc[i][j] = 0.f;

    for (int k0 = 0; k0 < K; k0 += 16) {
#pragma unroll
        for (int u = 0; u < 2; ++u) {
            const int idx = t + u * 256;       // 0..511
            const int row = idx >> 2;          // 128 rows
            const int c4  = (idx & 3) * 4;     // k sub-offset
            const float4 va = *(const float4*)(A + (size_t)(bm + row) * lda + k0 + c4);
            As[c4 + 0][row] = va.x; As[c4 + 1][row] = va.y;
            As[c4 + 2][row] = va.z; As[c4 + 3][row] = va.w;
            const float4 vb = *(const float4*)(W + (size_t)(bn + row) * K + k0 + c4);
            Bs[c4 + 0][row] = vb.x; Bs[c4 + 1][row] = vb.y;
            Bs[c4 + 2][row] = vb.z; Bs[c4 + 3][row] = vb.w;
        }
        __syncthreads();
#pragma unroll
        for (int kk = 0; kk < 16; ++kk) {
            float a[8], b[8];
            *(float4*)(a + 0) = *(const float4*)&As[kk][ty * 8 + 0];
            *(float4*)(a + 4) = *(const float4*)&As[kk][ty * 8 + 4];
            *(float4*)(b + 0) = *(const float4*)&Bs[kk][tx * 8 + 0];
            *(float4*)(b + 4) = *(const float4*)&Bs[kk][tx * 8 + 4];
#pragma unroll
            for (int i = 0; i < 8; ++i)
#pragma unroll
                for (int j = 0; j < 8; ++j)
                    acc[i][j] = fmaf(a[i], b[j], acc[i][j]);
        }
        __syncthreads();
    }

    float bj[8];
#pragma unroll
    for (int j = 0; j < 8; ++j) bj[j] = bias[bn + tx * 8 + j];
#pragma unroll
    for (int i = 0; i < 8; ++i) {
        const size_t r = bm + ty * 8 + i;
        float* cp = C + r * (size_t)ldc + bn + tx * 8;
        float4 o0 = make_float4(acc[i][0] + bj[0], acc[i][1] + bj[1],
                                acc[i][2] + bj[2], acc[i][3] + bj[3]);
        float4 o1 = make_float4(acc[i][4] + bj[4], acc[i][5] + bj[5],
                                acc[i][6] + bj[6], acc[i][7] + bj[7]);
        *(float4*)(cp + 0) = o0;
        *(float4*)(cp + 4) = o1;
    }
}

// ---------------- gate GEMM: partial[cb][r] = sum_n relu(A@Wg1^T+bg1)[r][n] * wg2[n] ----------------
__global__ __launch_bounds__(256)
void sgemm_gate(const float* __restrict__ A, const float* __restrict__ W,
                const float* __restrict__ bias, const float* __restrict__ wg2,
                float* __restrict__ gpart, int M)
{
    __shared__ float As[16][136];
    __shared__ float Bs[16][136];
    const int bm = blockIdx.x * 128;
    const int bn = blockIdx.y * 128;
    const int t  = threadIdx.x;
    const int tx = t & 15, ty = t >> 4;
    const int K = 256;

    float acc[8][8];
#pragma unroll
    for (int i = 0; i < 8; ++i)
#pragma unroll
        for (int j = 0; j < 8; ++j) acc[i][j] = 0.f;

    for (int k0 = 0; k0 < K; k0 += 16) {
#pragma unroll
        for (int u = 0; u < 2; ++u) {
            const int idx = t + u * 256;
            const int row = idx >> 2;
            const int c4  = (idx & 3) * 4;
            const float4 va = *(const float4*)(A + (size_t)(bm + row) * K + k0 + c4);
            As[c4 + 0][row] = va.x; As[c4 + 1][row] = va.y;
            As[c4 + 2][row] = va.z; As[c4 + 3][row] = va.w;
            const float4 vb = *(const float4*)(W + (size_t)(bn + row) * K + k0 + c4);
            Bs[c4 + 0][row] = vb.x; Bs[c4 + 1][row] = vb.y;
            Bs[c4 + 2][row] = vb.z; Bs[c4 + 3][row] = vb.w;
        }
        __syncthreads();
#pragma unroll
        for (int kk = 0; kk < 16; ++kk) {
            float a[8], b[8];
            *(float4*)(a + 0) = *(const float4*)&As[kk][ty * 8 + 0];
            *(float4*)(a + 4) = *(const float4*)&As[kk][ty * 8 + 4];
            *(float4*)(b + 0) = *(const float4*)&Bs[kk][tx * 8 + 0];
            *(float4*)(b + 4) = *(const float4*)&Bs[kk][tx * 8 + 4];
#pragma unroll
            for (int i = 0; i < 8; ++i)
#pragma unroll
                for (int j = 0; j < 8; ++j)
                    acc[i][j] = fmaf(a[i], b[j], acc[i][j]);
        }
        __syncthreads();
    }

    float bj[8], wj[8];
#pragma unroll
    for (int j = 0; j < 8; ++j) {
        bj[j] = bias[bn + tx * 8 + j];
        wj[j] = wg2[bn + tx * 8 + j];
    }
    float gsum[8];
#pragma unroll
    for (int i = 0; i < 8; ++i) {
        float s = 0.f;
#pragma unroll
        for (int j = 0; j < 8; ++j) {
            float g = fmaxf(acc[i][j] + bj[j], 0.f);
            s = fmaf(g, wj[j], s);
        }
        gsum[i] = s;
    }
    // reduce across the 16 tx lanes (contiguous lanes within a wave)
#pragma unroll
    for (int off = 1; off < 16; off <<= 1)
#pragma unroll
        for (int i = 0; i < 8; ++i)
            gsum[i] += __shfl_xor(gsum[i], off);
    if (tx == 0) {
#pragma unroll
        for (int i = 0; i < 8; ++i)
            gpart[(size_t)blockIdx.y * M + bm + ty * 8 + i] = gsum[i];
    }
}

// ---------------- gate finalize: sigmoid(part0+part1+bg2) ----------------
__global__ __launch_bounds__(256)
void gate_fin(const float* __restrict__ gpart, const float* __restrict__ bg2,
              float* __restrict__ gate, int M)
{
    const int r = blockIdx.x * 256 + threadIdx.x;
    const float v = gpart[r] + gpart[(size_t)M + r] + bg2[0];
    gate[r] = 1.f / (1.f + expf(-v));
}

// ---------------- combined = gate*so + (1-gate)*cross ----------------
__global__ __launch_bounds__(256)
void combined_kernel(const float* __restrict__ so, const float* __restrict__ gate,
                     float* __restrict__ comb)
{
    const int b = blockIdx.x;
    const int d = threadIdx.x;
    const float s0 = so[((size_t)b * 4 + 0) * 256 + d];
    const float s1 = so[((size_t)b * 4 + 1) * 256 + d];
    const float s2 = so[((size_t)b * 4 + 2) * 256 + d];
    const float s3 = so[((size_t)b * 4 + 3) * 256 + d];
    const float cross = 0.25f * (s0 + s1 + s2 + s3);
    const float g0 = gate[b * 4 + 0], g1 = gate[b * 4 + 1];
    const float g2 = gate[b * 4 + 2], g3 = gate[b * 4 + 3];
    float* cb = comb + (size_t)b * 1024;
    cb[0 * 256 + d] = g0 * s0 + (1.f - g0) * cross;
    cb[1 * 256 + d] = g1 * s1 + (1.f - g1) * cross;
    cb[2 * 256 + d] = g2 * s2 + (1.f - g2) * cross;
    cb[3 * 256 + d] = g3 * s3 + (1.f - g3) * cross;
}

// ---------------- BatchNorm partial sums over 128-row stripes ----------------
__global__ __launch_bounds__(256)
void bn_part(const float* __restrict__ h, float* __restrict__ psum,
             float* __restrict__ psq)
{
    const int p = blockIdx.x;   // 64 stripes
    const int d = threadIdx.x;
    float s = 0.f, q = 0.f;
    for (int r = 0; r < 128; ++r) {
        const float v = h[((size_t)p * 128 + r) * 256 + d];
        s += v;
        q = fmaf(v, v, q);
    }
    psum[p * 256 + d] = s;
    psq[p * 256 + d]  = q;
}

__global__ __launch_bounds__(256)
void bn_fin(const float* __restrict__ psum, const float* __restrict__ psq,
            const float* __restrict__ gamma, const float* __restrict__ beta,
            float* __restrict__ scale, float* __restrict__ shift)
{
    const int d = threadIdx.x;
    float s = 0.f, q = 0.f;
    for (int p = 0; p < 64; ++p) { s += psum[p * 256 + d]; q += psq[p * 256 + d]; }
    const float mu  = s * (1.f / BSZ);
    const float var = q * (1.f / BSZ) - mu * mu;
    const float inv = rsqrtf(var + BN_EPS);
    const float sc  = gamma[d] * inv;
    scale[d] = sc;
    shift[d] = beta[d] - mu * sc;
}

// ---------------- final: out = relu(h*scale+shift) @ W2^T + b2 ----------------
__global__ __launch_bounds__(256)
void final_kernel(const float* __restrict__ h, const float* __restrict__ scale,
                  const float* __restrict__ shift, const float* __restrict__ W2,
                  const float* __restrict__ b2, float* __restrict__ out)
{
    __shared__ float W2s[26][260];    // swizzled: n -> (n>>6)*65 + (n&63)
    __shared__ float scs[256], shs[256];
    const int t = threadIdx.x;
    for (int u = t; u < 26 * 256; u += 256) {
        const int c = u >> 8, n = u & 255;
        W2s[c][(n >> 6) * 65 + (n & 63)] = W2[u];
    }
    scs[t] = scale[t];
    shs[t] = shift[t];
    __syncthreads();

    const int r = blockIdx.x * 64 + (t >> 2);
    const int p = t & 3;                       // n-quarter
    float acc[26];
#pragma unroll
    for (int c = 0; c < 26; ++c) acc[c] = 0.f;
    const float* hr = h + (size_t)r * 256 + p * 64;
#pragma unroll 4
    for (int i = 0; i < 64; ++i) {
        const int n = p * 64 + i;
        const float v = fmaxf(fmaf(hr[i], scs[n], shs[n]), 0.f);
        const int sw = p * 65 + i;
#pragma unroll
        for (int c = 0; c < 26; ++c)
            acc[c] = fmaf(v, W2s[c][sw], acc[c]);
    }
#pragma unroll
    for (int off = 1; off < 4; off <<= 1)
#pragma unroll
        for (int c = 0; c < 26; ++c)
            acc[c] += __shfl_xor(acc[c], off);
    if (p == 0) {
#pragma unroll
        for (int c = 0; c < 26; ++c)
            out[(size_t)r * 26 + c] = acc[c] + b2[c];
    }
}

// ---------------- launch ----------------
extern "C" void kernel_launch(void* const* d_in, const int* in_sizes, int n_in,
                              void* d_out, int out_size, void* d_ws, size_t ws_size,
                              hipStream_t stream)
{
    const float* x_ctx  = (const float*)d_in[0];
    const float* x_body = (const float*)d_in[1];
    const float* x_face = (const float*)d_in[2];
    const float* x_text = (const float*)d_in[3];
    const float* Wc = (const float*)d_in[4];  const float* bc = (const float*)d_in[5];
    const float* Wb = (const float*)d_in[6];  const float* bb = (const float*)d_in[7];
    const float* Wf = (const float*)d_in[8];  const float* bf = (const float*)d_in[9];
    const float* Wt = (const float*)d_in[10]; const float* bt = (const float*)d_in[11];
    const float* in_w  = (const float*)d_in[12]; const float* in_b  = (const float*)d_in[13];
    const float* out_w = (const float*)d_in[14]; const float* out_b = (const float*)d_in[15];
    const float* Wg1 = (const float*)d_in[16]; const float* bg1 = (const float*)d_in[17];
    const float* Wg2 = (const float*)d_in[18]; const float* bg2 = (const float*)d_in[19];
    const float* W1  = (const float*)d_in[20]; const float* b1  = (const float*)d_in[21];
    const float* gamma = (const float*)d_in[22]; const float* beta = (const float*)d_in[23];
    const float* W2  = (const float*)d_in[24]; const float* b2  = (const float*)d_in[25];

    float* ws    = (float*)d_ws;
    float* f     = ws + OFF_F;
    float* so    = ws + OFF_SO;
    float* comb  = ws + OFF_COMB;
    float* wvo   = ws + OFF_WVO;
    float* bvo   = ws + OFF_BVO;
    float* gpart = ws + OFF_GPART;
    float* gate  = ws + OFF_GATE;
    float* h     = ws + OFF_H;
    float* psum  = ws + OFF_PSUM;
    float* psq   = ws + OFF_PSQ;
    float* scale = ws + OFF_SCALE;
    float* shift = ws + OFF_SHIFT;

    // fused value->out projection weight
    wvo_kernel<<<256, 256, 0, stream>>>(in_w, in_b, out_w, out_b, wvo, bvo);

    // modality projections -> f [8192, 4, 256] (ldc = 1024, column offset = m*256)
    sgemm_nt<<<dim3(64, 2), 256, 0, stream>>>(x_ctx,  Wc, bc, f + 0 * 256, NCTX,  NCTX,  1024);
    sgemm_nt<<<dim3(64, 2), 256, 0, stream>>>(x_body, Wb, bb, f + 1 * 256, NBODY, NBODY, 1024);
    sgemm_nt<<<dim3(64, 2), 256, 0, stream>>>(x_face, Wf, bf, f + 2 * 256, NFACE, NFACE, 1024);
    sgemm_nt<<<dim3(64, 2), 256, 0, stream>>>(x_text, Wt, bt, f + 3 * 256, NTEXT, NTEXT, 1024);

    // self_out = f @ Wvo^T + bvo   [32768, 256]
    sgemm_nt<<<dim3(256, 2), 256, 0, stream>>>(f, wvo, bvo, so, 256, 256, 256);

    // gate partials, then sigmoid
    sgemm_gate<<<dim3(256, 2), 256, 0, stream>>>(so, Wg1, bg1, Wg2, gpart, 32768);
    gate_fin<<<128, 256, 0, stream>>>(gpart, bg2, gate, 32768);

    // combined [8192, 1024]
    combined_kernel<<<8192, 256, 0, stream>>>(so, gate, comb);

    // h = combined @ W1^T + b1   [8192, 256]
    sgemm_nt<<<dim3(64, 2), 256, 0, stream>>>(comb, W1, b1, h, 1024, 1024, 256);

    // batch-norm stats
    bn_part<<<64, 256, 0, stream>>>(h, psum, psq);
    bn_fin<<<1, 256, 0, stream>>>(psum, psq, gamma, beta, scale, shift);

    // normalize + relu + classifier
    final_kernel<<<128, 256, 0, stream>>>(h, scale, shift, W2, b2, (float*)d_out);
}

// Round 2
// 166.086 us; speedup vs baseline: 5.7403x; 5.7403x over previous
//
#include <hip/hip_runtime.h>
#include <math.h>

typedef __attribute__((ext_vector_type(8))) short bf16x8;
typedef __attribute__((ext_vector_type(4))) float f32x4;
typedef unsigned short u16;
typedef unsigned int u32;

#define BSZ   8192
#define BN_EPS 1e-5f

// ---------- helpers ----------
__device__ inline u16 f2bf(float x) {            // RNE fp32 -> bf16 (finite inputs)
    u32 u = __float_as_uint(x);
    u32 r = (u + 0x7FFFu + ((u >> 16) & 1u)) >> 16;
    return (u16)r;
}
__device__ inline float bf2f_lo(u32 p) { return __uint_as_float(p << 16); }
__device__ inline float bf2f_hi(u32 p) { return __uint_as_float(p & 0xFFFF0000u); }

__device__ inline void async_g2l(const void* g, void* l) {
    __builtin_amdgcn_global_load_lds(
        (const __attribute__((address_space(1))) void*)g,
        (__attribute__((address_space(3))) void*)l, 16, 0, 0);
}

// ---------- Wvo = out_w @ Wv, bvo = out_w @ bv + out_b (fp32, tiny) ----------
__global__ __launch_bounds__(256)
void wvo_kernel(const float* __restrict__ in_w, const float* __restrict__ in_b,
                const float* __restrict__ out_w, const float* __restrict__ out_b,
                float* __restrict__ wvo, float* __restrict__ bvo)
{
    const int i = blockIdx.x;
    const int j = threadIdx.x;
    const float* Wv = in_w + 512 * 256;
    float s = 0.f;
    for (int k = 0; k < 256; ++k)
        s = fmaf(out_w[i * 256 + k], Wv[k * 256 + j], s);
    wvo[i * 256 + j] = s;
    if (i == 0) {
        const float* bv = in_b + 512;
        float t = 0.f;
        for (int k = 0; k < 256; ++k)
            t = fmaf(out_w[j * 256 + k], bv[k], t);
        bvo[j] = t + out_b[j];
    }
}

// ---------- convert all weight matrices to bf16 (packed buffer) ----------
// elem offsets (u16): wvo 0, Wc 65536, Wb 589824, Wf 1114112, Wt 1245184,
//                     Wg1 1441792, W1 1507328   (total 1769472)
__global__ __launch_bounds__(256)
void cvt_weights(const float* __restrict__ wvo, const float* __restrict__ Wc,
                 const float* __restrict__ Wb,  const float* __restrict__ Wf,
                 const float* __restrict__ Wt,  const float* __restrict__ Wg1,
                 const float* __restrict__ W1f, u16* __restrict__ dst)
{
    int gid = blockIdx.x * 256 + threadIdx.x;    // unit = 8 floats
    const float* src; u16* d; int loc;
    if      (gid <   8192) { src = wvo; d = dst + 0;       loc = gid; }
    else if (gid <  73728) { src = Wc;  d = dst + 65536;   loc = gid - 8192; }
    else if (gid < 139264) { src = Wb;  d = dst + 589824;  loc = gid - 73728; }
    else if (gid < 155648) { src = Wf;  d = dst + 1114112; loc = gid - 139264; }
    else if (gid < 180224) { src = Wt;  d = dst + 1245184; loc = gid - 155648; }
    else if (gid < 188416) { src = Wg1; d = dst + 1441792; loc = gid - 180224; }
    else                   { src = W1f; d = dst + 1507328; loc = gid - 188416; }
    const float4 v0 = *(const float4*)(src + (size_t)loc * 8);
    const float4 v1 = *(const float4*)(src + (size_t)loc * 8 + 4);
    uint4 o;
    o.x = (u32)f2bf(v0.x) | ((u32)f2bf(v0.y) << 16);
    o.y = (u32)f2bf(v0.z) | ((u32)f2bf(v0.w) << 16);
    o.z = (u32)f2bf(v1.x) | ((u32)f2bf(v1.y) << 16);
    o.w = (u32)f2bf(v1.z) | ((u32)f2bf(v1.w) << 16);
    *(uint4*)(d + (size_t)loc * 8) = o;
}

// ---------- MFMA GEMM core ----------
// C[r][n] = sum_k A[r][k] * W[n][k] + bias[n],  tile BM=64 x BN=256 x BK=64
// 256 threads = 4 waves; wave w owns cols [w*64, w*64+64); 16x16x32 bf16 MFMA.
// LDS layout [row][chunk^(row&7)] where chunk = 16B unit of 8 bf16 along K.
// ASRC: 0 = A is bf16 (global_load_lds), 1 = A is fp32 (reg-stage + convert)
// EPI : 0 = bf16 out at row (bm+rt)*RMUL+ROFF, 1 = fp32 out, 2 = gate reduce
template<int ASRC, int EPI>
__device__ void gemm_core(const void* Ap, const u16* __restrict__ Wp,
                          const float* __restrict__ bias,
                          u16* __restrict__ outb, float* __restrict__ outf,
                          const float* __restrict__ wg2, float* __restrict__ gpart,
                          int K, int RMUL, int ROFF, int bm)
{
    __shared__ u16 As[64 * 64];
    __shared__ u16 Bs[256 * 64];
    const int t = threadIdx.x;
    const int w = t >> 6, l = t & 63;

    f32x4 acc[4][4];
    const f32x4 z = {0.f, 0.f, 0.f, 0.f};
#pragma unroll
    for (int i = 0; i < 4; ++i)
#pragma unroll
        for (int j = 0; j < 4; ++j) acc[i][j] = z;

    for (int k0 = 0; k0 < K; k0 += 64) {
        // ---- B staging (async, 8 x 1KB per wave) ----
#pragma unroll
        for (int it = 0; it < 8; ++it) {
            const int n  = it * 32 + w * 8 + (l >> 3);
            const int ch = (l & 7) ^ (n & 7);
            async_g2l(Wp + (size_t)n * K + k0 + ch * 8, Bs + it * 2048 + w * 512);
        }
        // ---- A staging ----
        if (ASRC == 0) {
            const u16* Ab = (const u16*)Ap;
#pragma unroll
            for (int it = 0; it < 2; ++it) {
                const int row = it * 32 + w * 8 + (l >> 3);
                const int ch  = (l & 7) ^ (row & 7);
                async_g2l(Ab + (size_t)(bm + row) * K + k0 + ch * 8,
                          As + it * 2048 + w * 512);
            }
        } else {
            const float* Af = (const float*)Ap;
            const int row = t >> 2, kq = t & 3;
            const float* g = Af + (size_t)(bm + row) * K + k0 + kq * 16;
            const float4 v0 = *(const float4*)(g + 0);
            const float4 v1 = *(const float4*)(g + 4);
            const float4 v2 = *(const float4*)(g + 8);
            const float4 v3 = *(const float4*)(g + 12);
            bf16x8 p0, p1;
            p0[0] = (short)f2bf(v0.x); p0[1] = (short)f2bf(v0.y);
            p0[2] = (short)f2bf(v0.z); p0[3] = (short)f2bf(v0.w);
            p0[4] = (short)f2bf(v1.x); p0[5] = (short)f2bf(v1.y);
            p0[6] = (short)f2bf(v1.z); p0[7] = (short)f2bf(v1.w);
            p1[0] = (short)f2bf(v2.x); p1[1] = (short)f2bf(v2.y);
            p1[2] = (short)f2bf(v2.z); p1[3] = (short)f2bf(v2.w);
            p1[4] = (short)f2bf(v3.x); p1[5] = (short)f2bf(v3.y);
            p1[6] = (short)f2bf(v3.z); p1[7] = (short)f2bf(v3.w);
            char* ab = (char*)As;
            *(bf16x8*)(ab + row * 128 + (((kq * 2 + 0) ^ (row & 7)) << 4)) = p0;
            *(bf16x8*)(ab + row * 128 + (((kq * 2 + 1) ^ (row & 7)) << 4)) = p1;
        }
        __syncthreads();
        // ---- compute ----
        const char* ab = (const char*)As;
        const char* bb = (const char*)Bs;
#pragma unroll
        for (int kk = 0; kk < 2; ++kk) {
            bf16x8 af[4], bq[4];
#pragma unroll
            for (int i = 0; i < 4; ++i) {
                const int row = i * 16 + (l & 15);
                const int ch  = (l >> 4) + kk * 4;
                af[i] = *(const bf16x8*)(ab + row * 128 + ((ch ^ (row & 7)) << 4));
            }
#pragma unroll
            for (int j = 0; j < 4; ++j) {
                const int n  = w * 64 + j * 16 + (l & 15);
                const int ch = (l >> 4) + kk * 4;
                bq[j] = *(const bf16x8*)(bb + n * 128 + ((ch ^ (n & 7)) << 4));
            }
#pragma unroll
            for (int i = 0; i < 4; ++i)
#pragma unroll
                for (int j = 0; j < 4; ++j)
                    acc[i][j] = __builtin_amdgcn_mfma_f32_16x16x32_bf16(
                        af[i], bq[j], acc[i][j], 0, 0, 0);
        }
        __syncthreads();
    }

    // ---- epilogue ----
    if (EPI == 2) {
        float s[4][4];
#pragma unroll
        for (int i = 0; i < 4; ++i)
#pragma unroll
            for (int r = 0; r < 4; ++r) s[i][r] = 0.f;
#pragma unroll
        for (int j = 0; j < 4; ++j) {
            const int col = w * 64 + j * 16 + (l & 15);
            const float bv = bias[col], wv = wg2[col];
#pragma unroll
            for (int i = 0; i < 4; ++i)
#pragma unroll
                for (int r = 0; r < 4; ++r)
                    s[i][r] += fmaxf(acc[i][j][r] + bv, 0.f) * wv;
        }
#pragma unroll
        for (int off = 1; off < 16; off <<= 1)
#pragma unroll
            for (int i = 0; i < 4; ++i)
#pragma unroll
                for (int r = 0; r < 4; ++r)
                    s[i][r] += __shfl_xor(s[i][r], off);
        if ((l & 15) == 0) {
#pragma unroll
            for (int i = 0; i < 4; ++i)
#pragma unroll
                for (int r = 0; r < 4; ++r)
                    gpart[(size_t)w * 32768 + bm + i * 16 + ((l >> 4) << 2) + r] = s[i][r];
        }
    } else {
#pragma unroll
        for (int j = 0; j < 4; ++j) {
            const int col = w * 64 + j * 16 + (l & 15);
            const float bv = bias[col];
#pragma unroll
            for (int i = 0; i < 4; ++i) {
#pragma unroll
                for (int r = 0; r < 4; ++r) {
                    const int rt = i * 16 + ((l >> 4) << 2) + r;
                    const float v = acc[i][j][r] + bv;
                    const size_t orow = (size_t)(bm + rt) * RMUL + ROFF;
                    if (EPI == 0) outb[orow * 256 + col] = f2bf(v);
                    else          outf[orow * 256 + col] = v;
                }
            }
        }
    }
}

template<int ASRC, int EPI>
__global__ __launch_bounds__(256)
void gemm_k(const void* Ap, const u16* __restrict__ Wp, const float* __restrict__ bias,
            u16* __restrict__ outb, float* __restrict__ outf,
            const float* __restrict__ wg2, float* __restrict__ gpart, int K)
{
    gemm_core<ASRC, EPI>(Ap, Wp, bias, outb, outf, wg2, gpart, K, 1, 0, blockIdx.x * 64);
}

// fused 4-modality projection: grid (128, 4); writes f as [32768][256] with row = b*4+m
__global__ __launch_bounds__(256)
void gemm_proj(const float* A0, const float* A1, const float* A2, const float* A3,
               const u16* Wp0, const u16* Wp1, const u16* Wp2, const u16* Wp3,
               const float* b0, const float* b1, const float* b2, const float* b3,
               u16* __restrict__ fb)
{
    const int m = blockIdx.y;
    const float* A = (m == 0) ? A0 : (m == 1) ? A1 : (m == 2) ? A2 : A3;
    const u16* W   = (m == 0) ? Wp0 : (m == 1) ? Wp1 : (m == 2) ? Wp2 : Wp3;
    const float* b = (m == 0) ? b0 : (m == 1) ? b1 : (m == 2) ? b2 : b3;
    const int K    = (m == 0) ? 2048 : (m == 1) ? 2048 : (m == 2) ? 512 : 768;
    gemm_core<1, 0>(A, W, b, fb, nullptr, nullptr, nullptr, K, 4, m, blockIdx.x * 64);
}

// ---------- gate finalize ----------
__global__ __launch_bounds__(256)
void gate_fin(const float* __restrict__ gp, const float* __restrict__ bg2,
              float* __restrict__ gate)
{
    const int r = blockIdx.x * 256 + threadIdx.x;
    const float v = gp[r] + gp[32768 + r] + gp[65536 + r] + gp[98304 + r] + bg2[0];
    gate[r] = 1.f / (1.f + expf(-v));
}

// ---------- combined = gate*so + (1-gate)*cross ; bf16 in/out ----------
__global__ __launch_bounds__(256)
void combined_k(const u16* __restrict__ so, const float* __restrict__ gate,
                u16* __restrict__ comb)
{
    const int idx = blockIdx.x * 256 + threadIdx.x;    // 8192*128
    const int b = idx >> 7, p = idx & 127;
    const u32* s32 = (const u32*)so;
    u32* c32 = (u32*)comb;
    float lo[4], hi[4], gv[4];
#pragma unroll
    for (int m = 0; m < 4; ++m) {
        const u32 pk = s32[(size_t)(b * 4 + m) * 128 + p];
        lo[m] = bf2f_lo(pk); hi[m] = bf2f_hi(pk);
        gv[m] = gate[b * 4 + m];
    }
    const float cl = 0.25f * (lo[0] + lo[1] + lo[2] + lo[3]);
    const float ch = 0.25f * (hi[0] + hi[1] + hi[2] + hi[3]);
#pragma unroll
    for (int m = 0; m < 4; ++m) {
        const float ol = gv[m] * lo[m] + (1.f - gv[m]) * cl;
        const float oh = gv[m] * hi[m] + (1.f - gv[m]) * ch;
        c32[(size_t)b * 512 + m * 128 + p] = (u32)f2bf(ol) | ((u32)f2bf(oh) << 16);
    }
}

// ---------- BatchNorm partials / finalize ----------
__global__ __launch_bounds__(256)
void bn_part(const float* __restrict__ h, float* __restrict__ psum,
             float* __restrict__ psq)
{
    const int p = blockIdx.x;
    const int d = threadIdx.x;
    float s = 0.f, q = 0.f;
    for (int r = 0; r < 128; ++r) {
        const float v = h[((size_t)p * 128 + r) * 256 + d];
        s += v;
        q = fmaf(v, v, q);
    }
    psum[p * 256 + d] = s;
    psq[p * 256 + d]  = q;
}

__global__ __launch_bounds__(256)
void bn_fin(const float* __restrict__ psum, const float* __restrict__ psq,
            const float* __restrict__ gamma, const float* __restrict__ beta,
            float* __restrict__ scale, float* __restrict__ shift)
{
    const int d = threadIdx.x;
    float s = 0.f, q = 0.f;
    for (int p = 0; p < 64; ++p) { s += psum[p * 256 + d]; q += psq[p * 256 + d]; }
    const float mu  = s * (1.f / BSZ);
    const float var = q * (1.f / BSZ) - mu * mu;
    const float inv = rsqrtf(var + BN_EPS);
    const float sc  = gamma[d] * inv;
    scale[d] = sc;
    shift[d] = beta[d] - mu * sc;
}

// ---------- final: out = relu(h*scale+shift) @ W2^T + b2 ----------
__global__ __launch_bounds__(256)
void final_kernel(const float* __restrict__ h, const float* __restrict__ scale,
                  const float* __restrict__ shift, const float* __restrict__ W2,
                  const float* __restrict__ b2, float* __restrict__ out)
{
    __shared__ float W2s[26][260];
    __shared__ float scs[256], shs[256];
    const int t = threadIdx.x;
    for (int u = t; u < 26 * 256; u += 256) {
        const int c = u >> 8, n = u & 255;
        W2s[c][(n >> 6) * 65 + (n & 63)] = W2[u];
    }
    scs[t] = scale[t];
    shs[t] = shift[t];
    __syncthreads();

    const int r = blockIdx.x * 64 + (t >> 2);
    const int p = t & 3;
    float acc[26];
#pragma unroll
    for (int c = 0; c < 26; ++c) acc[c] = 0.f;
    const float* hr = h + (size_t)r * 256 + p * 64;
#pragma unroll 4
    for (int i = 0; i < 64; ++i) {
        const int n = p * 64 + i;
        const float v = fmaxf(fmaf(hr[i], scs[n], shs[n]), 0.f);
        const int sw = p * 65 + i;
#pragma unroll
        for (int c = 0; c < 26; ++c)
            acc[c] = fmaf(v, W2s[c][sw], acc[c]);
    }
#pragma unroll
    for (int off = 1; off < 4; off <<= 1)
#pragma unroll
        for (int c = 0; c < 26; ++c)
            acc[c] += __shfl_xor(acc[c], off);
    if (p == 0) {
#pragma unroll
        for (int c = 0; c < 26; ++c)
            out[(size_t)r * 26 + c] = acc[c] + b2[c];
    }
}

// ---------- launch ----------
extern "C" void kernel_launch(void* const* d_in, const int* in_sizes, int n_in,
                              void* d_out, int out_size, void* d_ws, size_t ws_size,
                              hipStream_t stream)
{
    const float* x_ctx  = (const float*)d_in[0];
    const float* x_body = (const float*)d_in[1];
    const float* x_face = (const float*)d_in[2];
    const float* x_text = (const float*)d_in[3];
    const float* Wc = (const float*)d_in[4];  const float* bc = (const float*)d_in[5];
    const float* Wb = (const float*)d_in[6];  const float* bb = (const float*)d_in[7];
    const float* Wf = (const float*)d_in[8];  const float* bf = (const float*)d_in[9];
    const float* Wt = (const float*)d_in[10]; const float* bt = (const float*)d_in[11];
    const float* in_w  = (const float*)d_in[12]; const float* in_b  = (const float*)d_in[13];
    const float* out_w = (const float*)d_in[14]; const float* out_b = (const float*)d_in[15];
    const float* Wg1 = (const float*)d_in[16]; const float* bg1 = (const float*)d_in[17];
    const float* Wg2 = (const float*)d_in[18]; const float* bg2 = (const float*)d_in[19];
    const float* W1  = (const float*)d_in[20]; const float* b1  = (const float*)d_in[21];
    const float* gamma = (const float*)d_in[22]; const float* beta = (const float*)d_in[23];
    const float* W2  = (const float*)d_in[24]; const float* b2  = (const float*)d_in[25];

    char* wsb = (char*)d_ws;
    u16*   f_bf  = (u16*)(wsb + 0);                    // 16 MB  [32768][256]
    u16*   comb  = f_bf;                               // overlay (f dead after so-GEMM)
    u16*   so_bf = (u16*)(wsb + (16u << 20));          // 16 MB  [32768][256]
    float* h     = (float*)(wsb + (16u << 20));        // overlay (so dead after combined)
    u16*   wpb   = (u16*)(wsb + (32u << 20));          // 3.54 MB packed bf16 weights
    float* wvo   = (float*)(wsb + (36u << 20));        // 256 KB
    float* bvo   = (float*)(wsb + (36u << 20) + 262144);
    float* gpart = (float*)(wsb + (37u << 20));        // 512 KB  [4][32768]
    float* gate  = (float*)(wsb + (38u << 20));        // 128 KB
    float* psum  = (float*)(wsb + (39u << 20));
    float* psq   = (float*)(wsb + (39u << 20) + 65536);
    float* scale = (float*)(wsb + (39u << 20) + 131072);
    float* shift = (float*)(wsb + (39u << 20) + 135168);

    u16* wvo_bf = wpb + 0;
    u16* wc_bf  = wpb + 65536;
    u16* wb_bf  = wpb + 589824;
    u16* wf_bf  = wpb + 1114112;
    u16* wt_bf  = wpb + 1245184;
    u16* wg1_bf = wpb + 1441792;
    u16* w1_bf  = wpb + 1507328;

    // 1) fused value->out projection (fp32) then all weight converts
    wvo_kernel<<<256, 256, 0, stream>>>(in_w, in_b, out_w, out_b, wvo, bvo);
    cvt_weights<<<864, 256, 0, stream>>>(wvo, Wc, Wb, Wf, Wt, Wg1, W1, wpb);

    // 2) fused modality projections -> f_bf [32768][256] (row = b*4+m)
    gemm_proj<<<dim3(128, 4), 256, 0, stream>>>(x_ctx, x_body, x_face, x_text,
                                                wc_bf, wb_bf, wf_bf, wt_bf,
                                                bc, bb, bf, bt, f_bf);

    // 3) self_out = f @ Wvo^T + bvo  -> so_bf
    gemm_k<0, 0><<<512, 256, 0, stream>>>(f_bf, wvo_bf, bvo, so_bf, nullptr,
                                          nullptr, nullptr, 256);

    // 4) gate partials (relu(so@Wg1^T+bg1) . wg2 per row), then sigmoid
    gemm_k<0, 2><<<512, 256, 0, stream>>>(so_bf, wg1_bf, bg1, nullptr, nullptr,
                                          Wg2, gpart, 256);
    gate_fin<<<128, 256, 0, stream>>>(gpart, bg2, gate);

    // 5) combined -> comb (overlays f_bf)  [8192][1024] bf16
    combined_k<<<4096, 256, 0, stream>>>(so_bf, gate, comb);

    // 6) h = comb @ W1^T + b1 -> h fp32 (overlays so_bf)
    gemm_k<0, 1><<<128, 256, 0, stream>>>(comb, w1_bf, b1, nullptr, h,
                                          nullptr, nullptr, 1024);

    // 7) batch-norm stats + final classifier
    bn_part<<<64, 256, 0, stream>>>(h, psum, psq);
    bn_fin<<<1, 256, 0, stream>>>(psum, psq, gamma, beta, scale, shift);
    final_kernel<<<128, 256, 0, stream>>>(h, scale, shift, W2, b2, (float*)d_out);
}